// Round 1
// baseline (497.527 us; speedup 1.0000x reference)
//
#include <hip/hip_runtime.h>

namespace {

constexpr int LEN   = 160;
constexpr int PLANE = LEN * LEN;          // 25600
constexpr int TOTAL = 2 * LEN * LEN * LEN; // 8,192,000 (B=2, C=1)
constexpr float INV_SZ = 1.0f / 125.0f;   // 1/K^3, K=5
constexpr float EPS_   = 1e-10f;

// ---------------------------------------------------------------------------
// 1D box filter (radius 2, replicate/clamp boundary) along axis with compile-
// time STRIDE (1 = W, 160 = H, 25600 = D). SQ=1 squares the input on the fly.
// ---------------------------------------------------------------------------
template <int SQ, int STRIDE>
__global__ __launch_bounds__(256) void box1d(const float* __restrict__ in,
                                             float* __restrict__ out) {
  int idx = blockIdx.x * 256 + threadIdx.x;
  if (idx >= TOTAL) return;
  int pos = (idx / STRIDE) % LEN;  // coordinate along filtered axis
  float s = 0.0f;
#pragma unroll
  for (int k = -2; k <= 2; ++k) {
    int p = pos + k;
    p = p < 0 ? 0 : (p > LEN - 1 ? LEN - 1 : p);
    float v = in[idx + (p - pos) * STRIDE];
    if (SQ) v *= v;
    s += v;
  }
  out[idx] = s;
}

// d = x - bs/125   (dst may alias x; read-before-write within the thread)
__global__ __launch_bounds__(256) void ew_diff(const float* __restrict__ x,
                                               const float* __restrict__ bs,
                                               float* __restrict__ dst) {
  int i = blockIdx.x * 256 + threadIdx.x;
  if (i >= TOTAL) return;
  float xv = x[i];
  dst[i] = xv - bs[i] * INV_SZ;
}

// d /= (sqrt(ss/125) + eps)   in place
__global__ __launch_bounds__(256) void ew_norm(float* __restrict__ d,
                                               const float* __restrict__ ss) {
  int i = blockIdx.x * 256 + threadIdx.x;
  if (i >= TOTAL) return;
  float sig = sqrtf(ss[i] * INV_SZ) + EPS_;
  d[i] = d[i] / sig;
}

// p = nF * (dM / (sqrt(ssM/125) + eps))   in place on nF
__global__ __launch_bounds__(256) void ew_norm_mul(float* __restrict__ nf,
                                                   const float* __restrict__ dm,
                                                   const float* __restrict__ ss) {
  int i = blockIdx.x * 256 + threadIdx.x;
  if (i >= TOTAL) return;
  float sig = sqrtf(ss[i] * INV_SZ) + EPS_;
  nf[i] = nf[i] * (dm[i] / sig);
}

// out -= sum(cross^2 * mask)  (d_out pre-zeroed via hipMemsetAsync)
__global__ __launch_bounds__(256) void reduce_k(const float* __restrict__ cross,
                                                const float* __restrict__ mask,
                                                float* __restrict__ out) {
  int tid = blockIdx.x * 256 + threadIdx.x;
  int gsz = gridDim.x * 256;
  float acc = 0.0f;
  for (int i = tid; i < TOTAL; i += gsz) {
    float c = cross[i];
    acc += c * c * mask[i];
  }
  // wave-64 shuffle reduce
#pragma unroll
  for (int off = 32; off > 0; off >>= 1) acc += __shfl_down(acc, off, 64);
  __shared__ float wsum[4];
  int lane = threadIdx.x & 63, wid = threadIdx.x >> 6;
  if (lane == 0) wsum[wid] = acc;
  __syncthreads();
  if (threadIdx.x == 0) {
    float t = wsum[0] + wsum[1] + wsum[2] + wsum[3];
    atomicAdd(out, -t);
  }
}

}  // namespace

extern "C" void kernel_launch(void* const* d_in, const int* in_sizes, int n_in,
                              void* d_out, int out_size, void* d_ws, size_t ws_size,
                              hipStream_t stream) {
  const float* F    = (const float*)d_in[0];
  const float* M    = (const float*)d_in[1];
  const float* mask = (const float*)d_in[2];
  float* out = (float*)d_out;

  const size_t bufB = (size_t)TOTAL * sizeof(float);
  char* ws = (char*)d_ws;
  float* T0 = (float*)ws;            // scratch / box results
  float* T1 = (float*)(ws + bufB);   // scratch
  float* T2;                         // dF -> nF -> p
  float* T3;                         // dM
  if (ws_size >= 4 * bufB) {
    T2 = (float*)(ws + 2 * bufB);
    T3 = (float*)(ws + 3 * bufB);
  } else {
    // Inputs are restored from pristine copies before every launch, and the
    // sequencing below consumes F/M before overwriting them.
    T2 = (float*)d_in[0];
    T3 = (float*)d_in[1];
  }

  const int blocks = (TOTAL + 255) / 256;
  dim3 grd(blocks), blk(256);

  hipMemsetAsync(d_out, 0, sizeof(float), stream);

  // --- bsF = box3(F); dF = F - bsF/125  (into T2, may alias F) ---
  box1d<0, 1>     <<<grd, blk, 0, stream>>>(F,  T0);
  box1d<0, LEN>   <<<grd, blk, 0, stream>>>(T0, T1);
  box1d<0, PLANE> <<<grd, blk, 0, stream>>>(T1, T0);
  ew_diff         <<<grd, blk, 0, stream>>>(F, T0, T2);

  // --- bsM = box3(M); dM = M - bsM/125  (into T3, may alias M) ---
  box1d<0, 1>     <<<grd, blk, 0, stream>>>(M,  T0);
  box1d<0, LEN>   <<<grd, blk, 0, stream>>>(T0, T1);
  box1d<0, PLANE> <<<grd, blk, 0, stream>>>(T1, T0);
  ew_diff         <<<grd, blk, 0, stream>>>(M, T0, T3);

  // --- ssF = box3(dF^2); nF = dF / (sqrt(ssF/125)+eps)  in place on T2 ---
  box1d<1, 1>     <<<grd, blk, 0, stream>>>(T2, T0);
  box1d<0, LEN>   <<<grd, blk, 0, stream>>>(T0, T1);
  box1d<0, PLANE> <<<grd, blk, 0, stream>>>(T1, T0);
  ew_norm         <<<grd, blk, 0, stream>>>(T2, T0);

  // --- ssM = box3(dM^2); p = nF * (dM/(sqrt(ssM/125)+eps))  in place on T2 ---
  box1d<1, 1>     <<<grd, blk, 0, stream>>>(T3, T0);
  box1d<0, LEN>   <<<grd, blk, 0, stream>>>(T0, T1);
  box1d<0, PLANE> <<<grd, blk, 0, stream>>>(T1, T0);
  ew_norm_mul     <<<grd, blk, 0, stream>>>(T2, T3, T0);

  // --- cross = box3(p) ---
  box1d<0, 1>     <<<grd, blk, 0, stream>>>(T2, T0);
  box1d<0, LEN>   <<<grd, blk, 0, stream>>>(T0, T1);
  box1d<0, PLANE> <<<grd, blk, 0, stream>>>(T1, T0);

  // --- out = -sum(cross^2 * mask) ---
  reduce_k        <<<dim3(1024), blk, 0, stream>>>(T0, mask, out);
}

// Round 2
// 279.576 us; speedup vs baseline: 1.7796x; 1.7796x over previous
//
#include <hip/hip_runtime.h>

namespace {

constexpr int LEN   = 160;
constexpr int PLANE = LEN * LEN;            // 25600
constexpr int VOL   = LEN * PLANE;          // 4,096,000 per batch
constexpr float INV_SZ = 1.0f / 125.0f;     // 1/K^3, K=5
constexpr float EPS_   = 1e-10f;

constexpr int TX = 32, TY = 32, ZC = 16;    // output tile
constexpr int RX = TX + 4, RY = TY + 4;     // 36x36 halo'd plane
constexpr int NRAW = RX * RY;               // 1296
constexpr int NXS  = TX * RY;               // 1152
constexpr int NPL  = TX * TY;               // 1024
constexpr int NCHZ = LEN / ZC;              // 10 z-chunks
constexpr int BLK  = 512;

__device__ __forceinline__ int clampi(int v) {
  return v < 0 ? 0 : (v > LEN - 1 ? LEN - 1 : v);
}

// ---------------------------------------------------------------------------
// Two-field slab box3. MODE 0: outA=inA-box(inA)/125, outB likewise (stage A).
// MODE 1: square on load; outA = (inA/(sqrt(boxA/125)+eps))*(inB/(sqrt(boxB/125)+eps)).
// ---------------------------------------------------------------------------
template <int MODE>
__global__ __launch_bounds__(BLK) void slab2(const float* __restrict__ inA,
                                             const float* __restrict__ inB,
                                             float* __restrict__ outA,
                                             float* __restrict__ outB) {
  __shared__ float rawA[RY][RX], rawB[RY][RX];
  __shared__ float xsA[RY][TX],  xsB[RY][TX];
  __shared__ float czA[5][TY][TX], czB[5][TY][TX];

  const int tid = threadIdx.x;
  const int x0 = blockIdx.x * TX;
  const int y0 = blockIdx.y * TY;
  const int z0 = (blockIdx.z % NCHZ) * ZC;
  const size_t base = (size_t)(blockIdx.z / NCHZ) * VOL;

  for (int zp = z0 - 2; zp <= z0 + ZC + 1; ++zp) {
    const int gz = clampi(zp);
    const float* pA = inA + base + (size_t)gz * PLANE;
    const float* pB = inB + base + (size_t)gz * PLANE;

    for (int i = tid; i < NRAW; i += BLK) {
      int ly = i / RX, lx = i % RX;
      int gx = clampi(x0 - 2 + lx);
      int gy = clampi(y0 - 2 + ly);
      float a = pA[gy * LEN + gx];
      float b = pB[gy * LEN + gx];
      if (MODE == 1) { a *= a; b *= b; }
      rawA[ly][lx] = a; rawB[ly][lx] = b;
    }
    __syncthreads();

    for (int i = tid; i < NXS; i += BLK) {
      int ly = i / TX, lx = i % TX;
      float sa = 0.f, sb = 0.f;
#pragma unroll
      for (int k = 0; k < 5; ++k) { sa += rawA[ly][lx + k]; sb += rawB[ly][lx + k]; }
      xsA[ly][lx] = sa; xsB[ly][lx] = sb;
    }
    __syncthreads();

    const int slot = (zp + 10) % 5;
    for (int i = tid; i < NPL; i += BLK) {
      int ly = i / TX, lx = i % TX;
      float sa = 0.f, sb = 0.f;
#pragma unroll
      for (int k = 0; k < 5; ++k) { sa += xsA[ly + k][lx]; sb += xsB[ly + k][lx]; }
      czA[slot][ly][lx] = sa; czB[slot][ly][lx] = sb;
    }
    __syncthreads();

    if (zp >= z0 + 2) {
      const int zo = zp - 2;
      for (int i = tid; i < NPL; i += BLK) {
        int ly = i / TX, lx = i % TX;
        float bsA = 0.f, bsB = 0.f;
#pragma unroll
        for (int s = 0; s < 5; ++s) { bsA += czA[s][ly][lx]; bsB += czB[s][ly][lx]; }
        size_t g = base + (size_t)zo * PLANE + (size_t)(y0 + ly) * LEN + (x0 + lx);
        if (MODE == 0) {
          outA[g] = inA[g] - bsA * INV_SZ;   // center reads hit L1/L2
          outB[g] = inB[g] - bsB * INV_SZ;
        } else {
          float sF = sqrtf(bsA * INV_SZ) + EPS_;
          float sM = sqrtf(bsB * INV_SZ) + EPS_;
          outA[g] = (inA[g] / sF) * (inB[g] / sM);
        }
      }
    }
  }
}

// ---------------------------------------------------------------------------
// Stage C: cross = box3(p); acc += cross^2 * mask; block-reduce -> atomicAdd.
// ---------------------------------------------------------------------------
__global__ __launch_bounds__(BLK) void slab1_reduce(const float* __restrict__ p,
                                                    const float* __restrict__ mask,
                                                    float* __restrict__ out) {
  __shared__ float raw[RY][RX];
  __shared__ float xs[RY][TX];
  __shared__ float cz[5][TY][TX];
  __shared__ float wsum[BLK / 64];

  const int tid = threadIdx.x;
  const int x0 = blockIdx.x * TX;
  const int y0 = blockIdx.y * TY;
  const int z0 = (blockIdx.z % NCHZ) * ZC;
  const size_t base = (size_t)(blockIdx.z / NCHZ) * VOL;

  float acc = 0.f;

  for (int zp = z0 - 2; zp <= z0 + ZC + 1; ++zp) {
    const int gz = clampi(zp);
    const float* pp = p + base + (size_t)gz * PLANE;

    for (int i = tid; i < NRAW; i += BLK) {
      int ly = i / RX, lx = i % RX;
      int gx = clampi(x0 - 2 + lx);
      int gy = clampi(y0 - 2 + ly);
      raw[ly][lx] = pp[gy * LEN + gx];
    }
    __syncthreads();

    for (int i = tid; i < NXS; i += BLK) {
      int ly = i / TX, lx = i % TX;
      float s = 0.f;
#pragma unroll
      for (int k = 0; k < 5; ++k) s += raw[ly][lx + k];
      xs[ly][lx] = s;
    }
    __syncthreads();

    const int slot = (zp + 10) % 5;
    for (int i = tid; i < NPL; i += BLK) {
      int ly = i / TX, lx = i % TX;
      float s = 0.f;
#pragma unroll
      for (int k = 0; k < 5; ++k) s += xs[ly + k][lx];
      cz[slot][ly][lx] = s;
    }
    __syncthreads();

    if (zp >= z0 + 2) {
      const int zo = zp - 2;
      for (int i = tid; i < NPL; i += BLK) {
        int ly = i / TX, lx = i % TX;
        float bs = 0.f;
#pragma unroll
        for (int s = 0; s < 5; ++s) bs += cz[s][ly][lx];
        size_t g = base + (size_t)zo * PLANE + (size_t)(y0 + ly) * LEN + (x0 + lx);
        acc += bs * bs * mask[g];
      }
    }
  }

#pragma unroll
  for (int off = 32; off > 0; off >>= 1) acc += __shfl_down(acc, off, 64);
  int lane = tid & 63, wid = tid >> 6;
  if (lane == 0) wsum[wid] = acc;
  __syncthreads();
  if (tid == 0) {
    float t = 0.f;
#pragma unroll
    for (int w = 0; w < BLK / 64; ++w) t += wsum[w];
    atomicAdd(out, -t);
  }
}

}  // namespace

extern "C" void kernel_launch(void* const* d_in, const int* in_sizes, int n_in,
                              void* d_out, int out_size, void* d_ws, size_t ws_size,
                              hipStream_t stream) {
  const float* F    = (const float*)d_in[0];
  const float* M    = (const float*)d_in[1];
  const float* mask = (const float*)d_in[2];
  float* out = (float*)d_out;

  const size_t bufB = (size_t)(2 * VOL) * sizeof(float);
  char* ws = (char*)d_ws;
  float* dF = (float*)ws;                 // also reused: dF slot holds p after stage B
  float* dM = (float*)(ws + bufB);
  float* pB = (float*)(ws + 2 * bufB);

  hipMemsetAsync(d_out, 0, sizeof(float), stream);

  dim3 grd(LEN / TX, LEN / TY, NCHZ * 2), blk(BLK);

  // Stage A: dF = F - box3(F)/125 ; dM = M - box3(M)/125
  slab2<0><<<grd, blk, 0, stream>>>(F, M, dF, dM);
  // Stage B: p = (dF/(sqrt(box3(dF^2)/125)+eps)) * (dM/(sqrt(box3(dM^2)/125)+eps))
  slab2<1><<<grd, blk, 0, stream>>>(dF, dM, pB, nullptr);
  // Stage C: out = -sum(box3(p)^2 * mask)
  slab1_reduce<<<grd, blk, 0, stream>>>(pB, mask, out);
}

// Round 3
// 212.090 us; speedup vs baseline: 2.3458x; 1.3182x over previous
//
#include <hip/hip_runtime.h>

namespace {

constexpr int LEN   = 160;
constexpr int PLANE = LEN * LEN;            // 25600
constexpr int VOL   = LEN * PLANE;          // 4,096,000 per batch
constexpr float INV_SZ = 1.0f / 125.0f;
constexpr float EPS_   = 1e-10f;

constexpr int TX = 32, TY = 32, ZC = 16;
constexpr int RX = TX + 4, RY = TY + 4;     // 36
constexpr int NRAW = RX * RY;               // 1296
constexpr int NXS  = TX * RY;               // 1152
constexpr int NCHZ = LEN / ZC;              // 10
constexpr int BLK  = 512;                   // each thread owns 2 output pixels

__device__ __forceinline__ int clampi(int v) {
  return v < 0 ? 0 : (v > LEN - 1 ? LEN - 1 : v);
}

// ---------------------------------------------------------------------------
// Two-field slab box3, software-pipelined, 2 barriers/plane.
// MODE 0: outA = inA - box3(inA)/125 ; outB likewise.
// MODE 1: raw LDS holds unsquared values; xs squares on read.
//         outA = (inA/(sqrt(box3(inA^2)/125)+eps)) * (inB/(sqrt(box3(inB^2)/125)+eps))
// ---------------------------------------------------------------------------
template <int MODE>
__global__ __launch_bounds__(BLK) void slab2(const float* __restrict__ inA,
                                             const float* __restrict__ inB,
                                             float* __restrict__ outA,
                                             float* __restrict__ outB) {
  __shared__ float rawA[RY][RX], rawB[RY][RX];   // 10.4 KB
  __shared__ float xsA[RY][TX],  xsB[RY][TX];    //  9.2 KB

  const int tid = threadIdx.x;
  const int x0 = blockIdx.x * TX;
  const int y0 = blockIdx.y * TY;
  const int z0 = (blockIdx.z % NCHZ) * ZC;
  const size_t base = (size_t)(blockIdx.z / NCHZ) * VOL;

  // plane-invariant halo-load descriptors
  int off[3], lly[3], llx[3];
  bool act[3];
#pragma unroll
  for (int j = 0; j < 3; ++j) {
    int i = tid + j * BLK;
    act[j] = i < NRAW;
    int ii = act[j] ? i : 0;
    lly[j] = ii / RX; llx[j] = ii % RX;
    off[j] = clampi(y0 - 2 + lly[j]) * LEN + clampi(x0 - 2 + llx[j]);
  }

  // owned output pixels
  const int ly0 = tid >> 5,           lx0 = tid & 31;
  const int ly1 = (tid + BLK) >> 5,   lx1 = (tid + BLK) & 31;

  float pfA[3], pfB[3];
  float rzA[5][2], rzB[5][2];    // z-ring of xy-sums (registers)
  float cenA[3][2], cenB[3][2];  // center-value ring, lag 2

  auto loadPlane = [&](int zp) {
    const size_t pb = base + (size_t)clampi(zp) * PLANE;
#pragma unroll
    for (int j = 0; j < 3; ++j)
      if (act[j]) { pfA[j] = inA[pb + off[j]]; pfB[j] = inB[pb + off[j]]; }
  };
  auto depositLDS = [&]() {
#pragma unroll
    for (int j = 0; j < 3; ++j)
      if (act[j]) { rawA[lly[j]][llx[j]] = pfA[j]; rawB[lly[j]][llx[j]] = pfB[j]; }
  };

  loadPlane(z0 - 2);
  depositLDS();
  __syncthreads();

  for (int zp = z0 - 2; zp <= z0 + ZC + 1; ++zp) {
    if (zp <= z0 + ZC) loadPlane(zp + 1);   // prefetch in flight during compute

    // x-sums (squared on read for MODE 1)
#pragma unroll
    for (int j = 0; j < 3; ++j) {
      int i = tid + j * BLK;
      if (i < NXS) {
        int ly = i >> 5, lx = i & 31;
        float sa = 0.f, sb = 0.f;
#pragma unroll
        for (int k = 0; k < 5; ++k) {
          float a = rawA[ly][lx + k], b = rawB[ly][lx + k];
          if (MODE == 1) { a *= a; b *= b; }
          sa += a; sb += b;
        }
        xsA[ly][lx] = sa; xsB[ly][lx] = sb;
      }
    }
    // center stash (unsquared), ring shift: cen[0] ends up at lag 2
#pragma unroll
    for (int s = 0; s < 2; ++s)
#pragma unroll
      for (int p = 0; p < 2; ++p) {
        cenA[s][p] = cenA[s + 1][p]; cenB[s][p] = cenB[s + 1][p];
      }
    cenA[2][0] = rawA[ly0 + 2][lx0 + 2]; cenB[2][0] = rawB[ly0 + 2][lx0 + 2];
    cenA[2][1] = rawA[ly1 + 2][lx1 + 2]; cenB[2][1] = rawB[ly1 + 2][lx1 + 2];

    __syncthreads();                        // xs ready; all raw reads done

    if (zp <= z0 + ZC) depositLDS();        // raw <- plane zp+1 (waits on prefetch)

    // y-sums into register z-ring
#pragma unroll
    for (int s = 0; s < 4; ++s)
#pragma unroll
      for (int p = 0; p < 2; ++p) {
        rzA[s][p] = rzA[s + 1][p]; rzB[s][p] = rzB[s + 1][p];
      }
    {
      float sa0 = 0.f, sb0 = 0.f, sa1 = 0.f, sb1 = 0.f;
#pragma unroll
      for (int k = 0; k < 5; ++k) {
        sa0 += xsA[ly0 + k][lx0]; sb0 += xsB[ly0 + k][lx0];
        sa1 += xsA[ly1 + k][lx1]; sb1 += xsB[ly1 + k][lx1];
      }
      rzA[4][0] = sa0; rzB[4][0] = sb0; rzA[4][1] = sa1; rzB[4][1] = sb1;
    }

    if (zp >= z0 + 2) {
      const int zo = zp - 2;
      float bsA0 = 0.f, bsB0 = 0.f, bsA1 = 0.f, bsB1 = 0.f;
#pragma unroll
      for (int s = 0; s < 5; ++s) {
        bsA0 += rzA[s][0]; bsB0 += rzB[s][0];
        bsA1 += rzA[s][1]; bsB1 += rzB[s][1];
      }
      size_t g0 = base + (size_t)zo * PLANE + (size_t)(y0 + ly0) * LEN + (x0 + lx0);
      size_t g1 = base + (size_t)zo * PLANE + (size_t)(y0 + ly1) * LEN + (x0 + lx1);
      if (MODE == 0) {
        outA[g0] = cenA[0][0] - bsA0 * INV_SZ;
        outB[g0] = cenB[0][0] - bsB0 * INV_SZ;
        outA[g1] = cenA[0][1] - bsA1 * INV_SZ;
        outB[g1] = cenB[0][1] - bsB1 * INV_SZ;
      } else {
        float sF0 = sqrtf(bsA0 * INV_SZ) + EPS_, sM0 = sqrtf(bsB0 * INV_SZ) + EPS_;
        float sF1 = sqrtf(bsA1 * INV_SZ) + EPS_, sM1 = sqrtf(bsB1 * INV_SZ) + EPS_;
        outA[g0] = (cenA[0][0] / sF0) * (cenB[0][0] / sM0);
        outA[g1] = (cenA[0][1] / sF1) * (cenB[0][1] / sM1);
      }
    }
    __syncthreads();                        // raw(zp+1) ready; xs reads done
  }
}

// ---------------------------------------------------------------------------
// Stage C: cross = box3(p); acc += cross^2 * mask; block reduce -> atomicAdd.
// ---------------------------------------------------------------------------
__global__ __launch_bounds__(BLK) void slab1_reduce(const float* __restrict__ p,
                                                    const float* __restrict__ mask,
                                                    float* __restrict__ out) {
  __shared__ float raw[RY][RX];
  __shared__ float xs[RY][TX];
  __shared__ float wsum[BLK / 64];

  const int tid = threadIdx.x;
  const int x0 = blockIdx.x * TX;
  const int y0 = blockIdx.y * TY;
  const int z0 = (blockIdx.z % NCHZ) * ZC;
  const size_t base = (size_t)(blockIdx.z / NCHZ) * VOL;

  int off[3], lly[3], llx[3];
  bool act[3];
#pragma unroll
  for (int j = 0; j < 3; ++j) {
    int i = tid + j * BLK;
    act[j] = i < NRAW;
    int ii = act[j] ? i : 0;
    lly[j] = ii / RX; llx[j] = ii % RX;
    off[j] = clampi(y0 - 2 + lly[j]) * LEN + clampi(x0 - 2 + llx[j]);
  }
  const int ly0 = tid >> 5,         lx0 = tid & 31;
  const int ly1 = (tid + BLK) >> 5, lx1 = (tid + BLK) & 31;

  float pf[3];
  float rz[5][2];
  float acc = 0.f;

  auto loadPlane = [&](int zp) {
    const size_t pb = base + (size_t)clampi(zp) * PLANE;
#pragma unroll
    for (int j = 0; j < 3; ++j)
      if (act[j]) pf[j] = p[pb + off[j]];
  };
  auto depositLDS = [&]() {
#pragma unroll
    for (int j = 0; j < 3; ++j)
      if (act[j]) raw[lly[j]][llx[j]] = pf[j];
  };

  loadPlane(z0 - 2);
  depositLDS();
  __syncthreads();

  for (int zp = z0 - 2; zp <= z0 + ZC + 1; ++zp) {
    if (zp <= z0 + ZC) loadPlane(zp + 1);

#pragma unroll
    for (int j = 0; j < 3; ++j) {
      int i = tid + j * BLK;
      if (i < NXS) {
        int ly = i >> 5, lx = i & 31;
        float s = 0.f;
#pragma unroll
        for (int k = 0; k < 5; ++k) s += raw[ly][lx + k];
        xs[ly][lx] = s;
      }
    }
    __syncthreads();

    if (zp <= z0 + ZC) depositLDS();

#pragma unroll
    for (int s = 0; s < 4; ++s)
#pragma unroll
      for (int px = 0; px < 2; ++px) rz[s][px] = rz[s + 1][px];
    {
      float s0 = 0.f, s1 = 0.f;
#pragma unroll
      for (int k = 0; k < 5; ++k) { s0 += xs[ly0 + k][lx0]; s1 += xs[ly1 + k][lx1]; }
      rz[4][0] = s0; rz[4][1] = s1;
    }

    if (zp >= z0 + 2) {
      const int zo = zp - 2;
      float bs0 = 0.f, bs1 = 0.f;
#pragma unroll
      for (int s = 0; s < 5; ++s) { bs0 += rz[s][0]; bs1 += rz[s][1]; }
      size_t g0 = base + (size_t)zo * PLANE + (size_t)(y0 + ly0) * LEN + (x0 + lx0);
      size_t g1 = base + (size_t)zo * PLANE + (size_t)(y0 + ly1) * LEN + (x0 + lx1);
      acc += bs0 * bs0 * mask[g0];
      acc += bs1 * bs1 * mask[g1];
    }
    __syncthreads();
  }

#pragma unroll
  for (int o = 32; o > 0; o >>= 1) acc += __shfl_down(acc, o, 64);
  int lane = tid & 63, wid = tid >> 6;
  if (lane == 0) wsum[wid] = acc;
  __syncthreads();
  if (tid == 0) {
    float t = 0.f;
#pragma unroll
    for (int w = 0; w < BLK / 64; ++w) t += wsum[w];
    atomicAdd(out, -t);
  }
}

}  // namespace

extern "C" void kernel_launch(void* const* d_in, const int* in_sizes, int n_in,
                              void* d_out, int out_size, void* d_ws, size_t ws_size,
                              hipStream_t stream) {
  const float* F    = (const float*)d_in[0];
  const float* M    = (const float*)d_in[1];
  const float* mask = (const float*)d_in[2];
  float* out = (float*)d_out;

  const size_t bufB = (size_t)(2 * VOL) * sizeof(float);
  char* ws = (char*)d_ws;
  float* dF = (float*)ws;
  float* dM = (float*)(ws + bufB);
  float* pB = (float*)(ws + 2 * bufB);

  hipMemsetAsync(d_out, 0, sizeof(float), stream);

  dim3 grd(LEN / TX, LEN / TY, NCHZ * 2), blk(BLK);

  slab2<0><<<grd, blk, 0, stream>>>(F, M, dF, dM);
  slab2<1><<<grd, blk, 0, stream>>>(dF, dM, pB, nullptr);
  slab1_reduce<<<grd, blk, 0, stream>>>(pB, mask, out);
}